// Round 15
// baseline (423.664 us; speedup 1.0000x reference)
//
#include <hip/hip_runtime.h>
#include <math.h>

#define DI __device__ __forceinline__

DI float sigm(float x){ return 1.0f/(1.0f+__expf(-x)); }
DI float tanhx(float x){ float ax=fabsf(x); float e=__expf(2.0f*ax); float t=1.0f-2.0f/(e+1.0f); return copysignf(t,x); }
DI unsigned short f2bf(float x){ unsigned u=__float_as_uint(x); return (unsigned short)((u+0x7fffu+((u>>16)&1u))>>16); }
DI float bflo(unsigned u){ return __uint_as_float(u<<16); }
DI float bfhi(unsigned u){ return __uint_as_float(u&0xffff0000u); }

typedef __attribute__((ext_vector_type(8))) short bf16x8;
typedef __attribute__((ext_vector_type(4))) float f32x4;
#define MFMA16(a,b,c) __builtin_amdgcn_mfma_f32_16x16x32_bf16(a,b,c,0,0,0)

static constexpr int RS  = 296;
static constexpr int RSZ = 9472;
static constexpr int AS  = 40;

static constexpr size_t OFF_A   = 4194304;
static constexpr size_t OFF_AM  = OFF_A   + 32768;
static constexpr size_t OFF_ALV = OFF_AM  + 32768;
static constexpr size_t OFF_MU  = OFF_ALV + 32768;
static constexpr size_t OFF_SG  = OFF_MU  + 16384;

// lane-parallel 4x4 inverse: valid at lanes (r<4,c<4); all 64 lanes execute.
DI float inv4_lane(float Mv, int r, int c){
  int a0=(c==0)?1:0, a1=(c<=1)?2:1, a2=(c<=2)?3:2;
  int b0=(r==0)?1:0, b1=(r<=1)?2:1, b2=(r<=2)?3:2;
  float m00=__shfl(Mv,(a0<<3)|b0,64), m01=__shfl(Mv,(a0<<3)|b1,64), m02=__shfl(Mv,(a0<<3)|b2,64);
  float m10=__shfl(Mv,(a1<<3)|b0,64), m11=__shfl(Mv,(a1<<3)|b1,64), m12=__shfl(Mv,(a1<<3)|b2,64);
  float m20=__shfl(Mv,(a2<<3)|b0,64), m21=__shfl(Mv,(a2<<3)|b1,64), m22=__shfl(Mv,(a2<<3)|b2,64);
  float det3 = m00*(m11*m22-m12*m21) - m01*(m10*m22-m12*m20) + m02*(m10*m21-m11*m20);
  float adj = (((r+c)&1)? -det3 : det3);
  float det=0.f;
  #pragma unroll
  for(int i=0;i<4;i++)
    det += __shfl(Mv,(i<<3),64)*__shfl(adj,i,64);
  return adj*(1.0f/det);
}

// serial 4x4 inverse (used only in parallel J precompute, one per thread)
DI void inv4_serial(const float* m, float* o){
  float i0 = m[5]*m[10]*m[15]-m[5]*m[11]*m[14]-m[9]*m[6]*m[15]+m[9]*m[7]*m[14]+m[13]*m[6]*m[11]-m[13]*m[7]*m[10];
  float i4 = -m[4]*m[10]*m[15]+m[4]*m[11]*m[14]+m[8]*m[6]*m[15]-m[8]*m[7]*m[14]-m[12]*m[6]*m[11]+m[12]*m[7]*m[10];
  float i8 = m[4]*m[9]*m[15]-m[4]*m[11]*m[13]-m[8]*m[5]*m[15]+m[8]*m[7]*m[13]+m[12]*m[5]*m[11]-m[12]*m[7]*m[9];
  float i12= -m[4]*m[9]*m[14]+m[4]*m[10]*m[13]+m[8]*m[5]*m[14]-m[8]*m[6]*m[13]-m[12]*m[5]*m[10]+m[12]*m[6]*m[9];
  float i1 = -m[1]*m[10]*m[15]+m[1]*m[11]*m[14]+m[9]*m[2]*m[15]-m[9]*m[3]*m[14]-m[13]*m[2]*m[11]+m[13]*m[3]*m[10];
  float i5 = m[0]*m[10]*m[15]-m[0]*m[11]*m[14]-m[8]*m[2]*m[15]+m[8]*m[3]*m[14]+m[12]*m[2]*m[11]-m[12]*m[3]*m[10];
  float i9 = -m[0]*m[9]*m[15]+m[0]*m[11]*m[13]+m[8]*m[1]*m[15]-m[8]*m[3]*m[13]-m[12]*m[1]*m[11]+m[12]*m[3]*m[9];
  float i13= m[0]*m[9]*m[14]-m[0]*m[10]*m[13]-m[8]*m[1]*m[14]+m[8]*m[2]*m[13]+m[12]*m[1]*m[10]-m[12]*m[2]*m[9];
  float i2 = m[1]*m[6]*m[15]-m[1]*m[7]*m[14]-m[5]*m[2]*m[15]+m[5]*m[3]*m[14]+m[13]*m[2]*m[7]-m[13]*m[3]*m[6];
  float i6 = -m[0]*m[6]*m[15]+m[0]*m[7]*m[14]+m[4]*m[2]*m[15]-m[4]*m[3]*m[14]-m[12]*m[2]*m[7]+m[12]*m[3]*m[6];
  float i10= m[0]*m[5]*m[15]-m[0]*m[7]*m[13]-m[4]*m[1]*m[15]+m[4]*m[3]*m[13]+m[12]*m[1]*m[7]-m[12]*m[3]*m[5];
  float i14= -m[0]*m[5]*m[14]+m[0]*m[6]*m[13]+m[4]*m[1]*m[14]-m[4]*m[2]*m[13]-m[12]*m[1]*m[6]+m[12]*m[2]*m[5];
  float i3 = -m[1]*m[6]*m[11]+m[1]*m[7]*m[10]+m[5]*m[2]*m[11]-m[5]*m[3]*m[10]-m[9]*m[2]*m[7]+m[9]*m[3]*m[6];
  float i7 = m[0]*m[6]*m[11]-m[0]*m[7]*m[10]-m[4]*m[2]*m[11]+m[4]*m[3]*m[10]+m[8]*m[2]*m[7]-m[8]*m[3]*m[6];
  float i11= -m[0]*m[5]*m[11]+m[0]*m[7]*m[9]+m[4]*m[1]*m[11]-m[4]*m[3]*m[9]-m[8]*m[1]*m[7]+m[8]*m[3]*m[5];
  float i15= m[0]*m[5]*m[10]-m[0]*m[6]*m[9]-m[4]*m[1]*m[10]+m[4]*m[2]*m[9]+m[8]*m[1]*m[6]-m[8]*m[2]*m[5];
  float rd=1.0f/(m[0]*i0+m[1]*i4+m[2]*i8+m[3]*i12);
  o[0]=i0*rd; o[1]=i1*rd; o[2]=i2*rd; o[3]=i3*rd;
  o[4]=i4*rd; o[5]=i5*rd; o[6]=i6*rd; o[7]=i7*rd;
  o[8]=i8*rd; o[9]=i9*rd; o[10]=i10*rd; o[11]=i11*rd;
  o[12]=i12*rd; o[13]=i13*rd; o[14]=i14*rd; o[15]=i15*rd;
}

// ===================== k_prep =====================
__global__ __launch_bounds__(256) void k_prep(
    const float* __restrict__ Wc1, const float* __restrict__ Wc2,
    const float* __restrict__ Wt0, const float* __restrict__ Wt1, const float* __restrict__ Wt2,
    unsigned short* __restrict__ ws16)
{
  int idx = blockIdx.x*256 + threadIdx.x;
  int mat = idx/RSZ, rem = idx%RSZ;
  int co = rem/RS, t = rem%RS;
  float v = 0.f;
  if (t < 288){
    int tap = t>>5, ci = t&31;
    if      (mat==0) v = Wc1[co*288+ci*9+tap];
    else if (mat==1) v = Wc2[co*288+ci*9+tap];
    else if (mat==2) v = Wt0[ci*288+co*9+tap];
    else if (mat==3) v = Wt1[ci*288+co*9+tap];
    else             v = Wt2[ci*288+co*9+tap];
  }
  ws16[idx] = f2bf(v);
}

// ===================== Encoder =====================
struct EncSh {
  alignas(16) float img[1024];
  alignas(16) unsigned short h0T[9040];
  alignas(16) unsigned short h1T[2000];
  alignas(16) unsigned short BT1e[9472];
  alignas(16) unsigned short BT2e[9472];
  alignas(16) float feat[288];
};

__global__ __launch_bounds__(256) void k_enc(
    const float* __restrict__ x, const float* __restrict__ eps,
    const float* __restrict__ Wc0, const float* __restrict__ bc0,
    const float* __restrict__ bc1, const float* __restrict__ bc2,
    const float* __restrict__ Wm, const float* __restrict__ bm,
    const float* __restrict__ Wlv, const float* __restrict__ blv,
    const unsigned short* __restrict__ ws16,
    float* __restrict__ out)
{
  __shared__ EncSh E;
  const int n = blockIdx.x, tid = threadIdx.x;
  const int lane = tid & 63, wave = tid >> 6, g = lane >> 4, c15 = lane & 15;

  for (int i=tid;i<1024;i+=256) E.img[i]=x[(size_t)n*1024+i];
  {
    uint4* dst=(uint4*)E.BT1e;
    const uint4* src=(const uint4*)ws16;
    for (int i=tid;i<2368;i+=256) dst[i]=src[i];
  }
  if (tid<32){ E.h0T[225*AS+tid]=0; E.h1T[49*AS+tid]=0; }
  __syncthreads();

  for (int i=tid;i<7200;i+=256){
    int co=i&31, p=i>>5, oy=p/15, ox=p%15;
    float acc=bc0[co];
    const float* wp=Wc0+co*9;
    int base=2*oy*32+2*ox;
    #pragma unroll
    for(int ky=0;ky<3;ky++)
      #pragma unroll
      for(int kx=0;kx<3;kx++)
        acc += E.img[base+ky*32+kx]*wp[ky*3+kx];
    E.h0T[p*AS+co]=f2bf(fmaxf(acc,0.0f));
  }
  __syncthreads();

  {
    const int mt=wave;
    const int oy=mt*2+(c15>>3), ox=c15&7;
    f32x4 acc0={0.f,0.f,0.f,0.f}, acc1={0.f,0.f,0.f,0.f};
    #pragma unroll 1
    for (int ky=0;ky<3;ky++){
      #pragma unroll
      for (int kx=0;kx<3;kx++){
        int iy=2*oy+ky, ix=2*ox+kx;
        int pix=(iy<15&&ix<15)?(iy*15+ix):225;
        bf16x8 af=*(const bf16x8*)&E.h0T[pix*AS+g*8];
        int tap=ky*3+kx;
        bf16x8 b0=*(const bf16x8*)&E.BT1e[c15*RS+tap*32+g*8];
        bf16x8 b1=*(const bf16x8*)&E.BT1e[(c15+16)*RS+tap*32+g*8];
        acc0=MFMA16(af,b0,acc0);
        acc1=MFMA16(af,b1,acc1);
      }
    }
    float bA=bc1[c15], bB=bc1[c15+16];
    #pragma unroll
    for (int r=0;r<4;r++){
      int p16=g*4+r, oy2=mt*2+(p16>>3), ox2=p16&7;
      if (oy2<7 && ox2<7){
        E.h1T[(oy2*7+ox2)*AS+c15]   =f2bf(fmaxf(acc0[r]+bA,0.f));
        E.h1T[(oy2*7+ox2)*AS+c15+16]=f2bf(fmaxf(acc1[r]+bB,0.f));
      }
    }
  }
  __syncthreads();

  if (wave<2){
    const int nt=wave;
    const int valid=(c15<9);
    const int oy=c15/3, ox=c15-oy*3;
    f32x4 acc={0.f,0.f,0.f,0.f};
    #pragma unroll 1
    for (int ky=0;ky<3;ky++){
      #pragma unroll
      for (int kx=0;kx<3;kx++){
        int pix=valid?((2*oy+ky)*7+(2*ox+kx)):49;
        bf16x8 af=*(const bf16x8*)&E.h1T[pix*AS+g*8];
        int tap=ky*3+kx;
        bf16x8 bfr=*(const bf16x8*)&E.BT2e[(nt*16+c15)*RS+tap*32+g*8];
        acc=MFMA16(af,bfr,acc);
      }
    }
    float bb=bc2[nt*16+c15];
    #pragma unroll
    for (int r=0;r<4;r++){
      int p16=g*4+r;
      if (p16<9) E.feat[(nt*16+c15)*9+p16]=fmaxf(acc[r]+bb,0.f);
    }
  }
  __syncthreads();

  if (tid<64){
    const int j=tid>>3, kk=tid&7;
    float s1=0.f,s2=0.f;
    const float* wm=Wm+j*288;
    const float* wl=Wlv+j*288;
    #pragma unroll 6
    for(int m=kk*36;m<kk*36+36;m++){ float f=E.feat[m]; s1+=f*wm[m]; s2+=f*wl[m]; }
    #pragma unroll
    for(int d=4;d>0;d>>=1){ s1+=__shfl_down(s1,d,64); s2+=__shfl_down(s2,d,64); }
    if(kk==0){
      size_t o=(size_t)n*8+j;
      float am=s1+bm[j];
      float lv=sigm(s2+blv[j]);
      float av=am+eps[o]*__expf(0.5f*lv);
      out[OFF_AM+o]=am;
      out[OFF_ALV+o]=lv;
      out[OFF_A+o]=av;
    }
  }
}

// ===================== k_main: 32 seq blocks + 4096 decoder blocks =====================
struct DecSh {
  alignas(16) float aa[8];
  alignas(16) unsigned short d0T[400];
  alignas(16) unsigned short t0T[2000];
  alignas(16) unsigned short t1T[9040];
  alignas(16) unsigned short BT0[9472];
  alignas(16) unsigned short BT1[9472];
  alignas(16) unsigned short BT2[9472];
};
struct SeqSh {
  alignas(16) float a_loc[1024];
  alignas(16) float a0[8];
  alignas(16) float xvec[64];            // [a_prev(8); h(50); pad]
  alignas(16) unsigned short Wbf[13056]; // [204][64] bf16; rows 0..199 LSTM, 200..202 Wa, 203 zeros
  float alpha[384];
  float muf[512];
  float Sigf[2048];
  float Sigp[2048];
  float Jb[2048];
  float Amat[48];
  float Bmat[96];
  float Cmat[96];
  float gram[96];
  float mca[2048];   // [s][16]
  float zbu[1024];   // [s][8]
};
union MainSh { DecSh d; SeqSh q; };

__global__ __launch_bounds__(512) void k_main(
    const float* __restrict__ Wd, const float* __restrict__ bd,
    const float* __restrict__ bt0, const float* __restrict__ bt1, const float* __restrict__ bt2,
    const float* __restrict__ Wg, const float* __restrict__ bgp,
    const float* __restrict__ Ag, const float* __restrict__ Bg, const float* __restrict__ Cg,
    const float* __restrict__ a_init,
    const float* __restrict__ W_ih, const float* __restrict__ W_hh,
    const float* __restrict__ b_ih, const float* __restrict__ b_hh,
    const float* __restrict__ Wa, const float* __restrict__ ba,
    const unsigned short* __restrict__ ws16,
    float* __restrict__ out)
{
  __shared__ MainSh sh;
  const int tid=threadIdx.x;
  const float* aglob = out + OFF_A;

  if (blockIdx.x < 32){
    // ================= sequential path (one batch per block) =================
    __builtin_amdgcn_s_setprio(1);
    SeqSh& Q = sh.q;
    const int b=blockIdx.x;
    for (int i=tid;i<1024;i+=512){ int s=i>>3, j=i&7; Q.a_loc[i]=aglob[((size_t)s*32+b)*8+j]; }
    if (tid<8)  Q.a0[tid]=a_init[tid];
    if (tid<64) Q.xvec[tid]=(tid<8)?a_init[tid]:0.f;
    for (int i=tid;i<48;i+=512) Q.Amat[i]=Ag[i];
    for (int i=tid;i<96;i+=512){ Q.Bmat[i]=Bg[i]; Q.Cmat[i]=Cg[i]; }
    // Wbf fill: [row][64] bf16
    for (int idx=tid; idx<13056; idx+=512){
      int row=idx>>6, k=idx&63;
      float v=0.f;
      if (row<200){
        if (k<8) v=W_ih[row*8+k];
        else if (k<58) v=W_hh[row*50+(k-8)];
      } else if (row<203){
        if (k>=8 && k<58) v=Wa[(row-200)*50+(k-8)];
      }
      Q.Wbf[idx]=f2bf(v);
    }
    // KF wave-0 lane geometry
    const int r=tid>>3, c=tid&7;
    bool aid=false;
    if (tid<64){
      int ok=1;
      if (r<4&&c<4){
        float d=(r==c)?1.f:0.f;
        ok=(Ag[r*4+c]==d)&&(Ag[16+r*4+c]==d)&&(Ag[32+r*4+c]==d);
      }
      aid=(bool)__all(ok);
    }
    __syncthreads();
    // gram matrices
    if (tid<96){
      int which=tid>>4, e=tid&15, i2=e>>2, j2=e&3;
      float s2=0.f;
      if (which<3){
        const float* C=&Q.Cmat[which*32];
        #pragma unroll
        for(int m=0;m<8;m++) s2+=C[m*4+i2]*C[m*4+j2];
      } else {
        int k2=(which==5)?1:0, l2=(which==3)?1:2;
        const float* Ck=&Q.Cmat[k2*32];
        const float* Cl=&Q.Cmat[l2*32];
        #pragma unroll
        for(int m=0;m<8;m++) s2+=Ck[m*4+i2]*Cl[m*4+j2]+Cl[m*4+i2]*Ck[m*4+j2];
      }
      Q.gram[tid]=s2;
    }
    __syncthreads();

    // ---- LSTM: SINGLE WAVE (wave 0), zero barriers ----
    if (tid<64){
      const int j=tid;
      const bool gate=(j<50), lg=(j>=50 && j<53), act54=(j<54);
      int r0=(j<50)?j:((j<54)?(150+j):203);
      int r1=(j<50)?(50+j):203;
      int r2=(j<50)?(100+j):203;
      int r3=(j<50)?(150+j):203;
      float b0=0.f,b1=0.f,b2=0.f,b3=0.f;
      if (gate){
        b0=b_ih[j]+b_hh[j]; b1=b_ih[50+j]+b_hh[50+j];
        b2=b_ih[100+j]+b_hh[100+j]; b3=b_ih[150+j]+b_hh[150+j];
      } else if (lg) b0=ba[j-50];
      const unsigned short* w0=&Q.Wbf[r0*64];
      const unsigned short* w1=&Q.Wbf[r1*64];
      const unsigned short* w2=&Q.Wbf[r2*64];
      const unsigned short* w3=&Q.Wbf[r3*64];
      float creg=0.f;
      for (int s=0;s<128;s++){
        if (act54){
          float acc0=b0,acc1=b1,acc2=b2,acc3=b3;
          #pragma unroll
          for(int q=0;q<8;q++){
            float4 xa=*(const float4*)&Q.xvec[8*q];
            float4 xb=*(const float4*)&Q.xvec[8*q+4];
            uint4 u0=*(const uint4*)&w0[8*q];
            uint4 u1=*(const uint4*)&w1[8*q];
            uint4 u2=*(const uint4*)&w2[8*q];
            uint4 u3=*(const uint4*)&w3[8*q];
            acc0+=bflo(u0.x)*xa.x+bfhi(u0.x)*xa.y+bflo(u0.y)*xa.z+bfhi(u0.y)*xa.w
                 +bflo(u0.z)*xb.x+bfhi(u0.z)*xb.y+bflo(u0.w)*xb.z+bfhi(u0.w)*xb.w;
            acc1+=bflo(u1.x)*xa.x+bfhi(u1.x)*xa.y+bflo(u1.y)*xa.z+bfhi(u1.y)*xa.w
                 +bflo(u1.z)*xb.x+bfhi(u1.z)*xb.y+bflo(u1.w)*xb.z+bfhi(u1.w)*xb.w;
            acc2+=bflo(u2.x)*xa.x+bfhi(u2.x)*xa.y+bflo(u2.y)*xa.z+bfhi(u2.y)*xa.w
                 +bflo(u2.z)*xb.x+bfhi(u2.z)*xb.y+bflo(u2.w)*xb.z+bfhi(u2.w)*xb.w;
            acc3+=bflo(u3.x)*xa.x+bfhi(u3.x)*xa.y+bflo(u3.y)*xa.z+bfhi(u3.y)*xa.w
                 +bflo(u3.z)*xb.x+bfhi(u3.z)*xb.y+bflo(u3.w)*xb.z+bfhi(u3.w)*xb.w;
          }
          if (gate){
            float ig=sigm(acc0), fg=sigm(acc1), gg=tanhx(acc2), og=sigm(acc3);
            creg=fg*creg+ig*gg;
            Q.xvec[8+j]=og*tanhx(creg);
          }
          if (j<8) Q.xvec[j]=Q.a_loc[s*8+j];
          if (lg && s>0){
            float l0=__shfl(acc0,50,64), l1=__shfl(acc0,51,64), l2=__shfl(acc0,52,64);
            float mx=fmaxf(l0,fmaxf(l1,l2));
            float e0=__expf(l0-mx), e1=__expf(l1-mx), e2=__expf(l2-mx);
            float me=(j==50)?l0:((j==51)?l1:l2);
            Q.alpha[(s-1)*3+(j-50)]=__expf(me-mx)/(e0+e1+e2);
          }
        }
      }
      // tail: alpha[127] from h_127
      if (lg){
        float acc0=b0;
        #pragma unroll
        for(int q=0;q<8;q++){
          float4 xa=*(const float4*)&Q.xvec[8*q];
          float4 xb=*(const float4*)&Q.xvec[8*q+4];
          uint4 u0=*(const uint4*)&w0[8*q];
          acc0+=bflo(u0.x)*xa.x+bfhi(u0.x)*xa.y+bflo(u0.y)*xa.z+bfhi(u0.y)*xa.w
               +bflo(u0.z)*xb.x+bfhi(u0.z)*xb.y+bflo(u0.w)*xb.z+bfhi(u0.w)*xb.w;
        }
        float l0=__shfl(acc0,50,64), l1=__shfl(acc0,51,64), l2=__shfl(acc0,52,64);
        float mx=fmaxf(l0,fmaxf(l1,l2));
        float e0=__expf(l0-mx), e1=__expf(l1-mx), e2=__expf(l2-mx);
        float me=(j==50)?l0:((j==51)?l1:l2);
        Q.alpha[127*3+(j-50)]=__expf(me-mx)/(e0+e1+e2);
      }
    }
    __syncthreads();
    // ---- KF input tables: Mc[s][16], z/Bu[s][8] (parallel, all 512) ----
    for (int idx=tid; idx<2048; idx+=512){
      int s=idx>>4, e=idx&15;
      float al0=Q.alpha[s*3+0], al1=Q.alpha[s*3+1], al2=Q.alpha[s*3+2];
      Q.mca[idx]= al0*al0*Q.gram[e]    + al1*al1*Q.gram[16+e] + al2*al2*Q.gram[32+e]
                + al0*al1*Q.gram[48+e] + al0*al2*Q.gram[64+e] + al1*al2*Q.gram[80+e];
    }
    for (int idx=tid; idx<1024; idx+=512){
      int s=idx>>3, t=idx&7;
      float al0=Q.alpha[s*3+0], al1=Q.alpha[s*3+1], al2=Q.alpha[s*3+2];
      float res=0.f;
      if (t<4){
        const float* av=&Q.a_loc[s*8];
        #pragma unroll
        for(int k=0;k<3;k++){
          float d=0.f;
          const float* C=&Q.Cmat[k*32];
          #pragma unroll
          for(int m=0;m<8;m++) d+=C[m*4+t]*av[m];
          res+=((k==0)?al0:((k==1)?al1:al2))*d;
        }
      } else {
        int i=t-4;
        const float* uv=(s==0)?Q.a0:&Q.a_loc[(s-1)*8];
        #pragma unroll
        for(int k=0;k<3;k++){
          float d=0.f;
          const float* B=&Q.Bmat[k*32+i*8];
          #pragma unroll
          for(int m=0;m<8;m++) d+=B[m]*uv[m];
          res+=((k==0)?al0:((k==1)?al1:al2))*d;
        }
      }
      Q.zbu[idx]=res;
    }
    __syncthreads();
    // ---- KF loop (wave 0 only, barrier-free) ----
    if (tid<64){
      const bool act=(r<4&&c<4);
      const int cc=c&3, rr4=r&3;
      float mu0=0.f,mu1=0.f,mu2=0.f,mu3=0.f, Sg=0.f;
      for (int s3=0;s3<128;s3++){
        const float* mrow=&Q.mca[s3*16+cc*4];
        float mr0=mrow[0], mr1=mrow[1], mr2=mrow[2], mr3=mrow[3];
        float mc0=Q.mca[s3*16+cc], mc1=Q.mca[s3*16+4+cc], mc2=Q.mca[s3*16+8+cc], mc3=Q.mca[s3*16+12+cc];
        float zc=Q.zbu[s3*8+cc];
        float bu0=Q.zbu[s3*8+4], bu1=Q.zbu[s3*8+5], bu2=Q.zbu[s3*8+6], bu3=Q.zbu[s3*8+7];
        float mp0,mp1,mp2,mp3, Sp;
        if (aid){
          mp0=mu0+bu0; mp1=mu1+bu1; mp2=mu2+bu2; mp3=mu3+bu3;
          Sp=Sg+((r==c)?0.08f:0.f);
        } else {
          float al0=Q.alpha[s3*3+0], al1=Q.alpha[s3*3+1], al2=Q.alpha[s3*3+2];
          int e2=(rr4<<2)|cc;
          float At=al0*Q.Amat[e2]+al1*Q.Amat[16+e2]+al2*Q.Amat[32+e2];
          float mcc=(c==0)?mu0:((c==1)?mu1:((c==2)?mu2:((c==3)?mu3:0.f)));
          float qv=(c<4)?At*mcc:0.f;
          qv+=__shfl_xor(qv,1,64); qv+=__shfl_xor(qv,2,64);
          float bur=(rr4==0)?bu0:((rr4==1)?bu1:((rr4==2)?bu2:bu3));
          float rowv=qv+bur;
          mp0=__shfl(rowv,0,64); mp1=__shfl(rowv,8,64); mp2=__shfl(rowv,16,64); mp3=__shfl(rowv,24,64);
          float T=0.f;
          #pragma unroll
          for(int k=0;k<4;k++) T+=__shfl(At,(r<<3)|k,64)*__shfl(Sg,(k<<3)|c,64);
          float sp=0.f;
          #pragma unroll
          for(int k=0;k<4;k++) sp+=__shfl(T,(r<<3)|k,64)*__shfl(At,(c<<3)|k,64);
          Sp=sp+((r==c)?0.08f:0.f);
        }
        if (s3==0){ mp0=0.f;mp1=0.f;mp2=0.f;mp3=0.f; Sp=(r==c)?20.f:0.f; }
        if (act) Q.Sigp[s3*16+rr4*4+cc]=Sp;
        float wc=zc-(mr0*mp0+mr1*mp1+mr2*mp2+mr3*mp3);
        float gv=(r==c)?1.f:0.f;
        gv+=__shfl(Sp,(r<<3)|0,64)*mc0*(1.0f/0.03f);
        gv+=__shfl(Sp,(r<<3)|1,64)*mc1*(1.0f/0.03f);
        gv+=__shfl(Sp,(r<<3)|2,64)*mc2*(1.0f/0.03f);
        gv+=__shfl(Sp,(r<<3)|3,64)*mc3*(1.0f/0.03f);
        float Gi=inv4_lane(gv,r,c);
        float Sf=0.f;
        #pragma unroll
        for(int k=0;k<4;k++) Sf+=__shfl(Gi,(r<<3)|k,64)*__shfl(Sp,(k<<3)|c,64);
        if (act) Q.Sigf[s3*16+rr4*4+cc]=Sf;
        float p=(c<4)?Sf*wc:0.f;
        p+=__shfl_xor(p,1,64); p+=__shfl_xor(p,2,64);
        float mpr=(r==0)?mp0:((r==1)?mp1:((r==2)?mp2:mp3));
        float mufr=mpr+p*(1.0f/0.03f);
        if (r<4&&c==0) Q.muf[s3*4+r]=mufr;
        mu0=__shfl(mufr,0,64); mu1=__shfl(mufr,8,64); mu2=__shfl(mufr,16,64); mu3=__shfl(mufr,24,64);
        Sg=Sf;
      }
    }
    __syncthreads();
    // ---- RTS: J_n precompute (parallel over n) ----
    if (tid<127){
      const int n2=tid;
      float al0=Q.alpha[(n2+1)*3+0], al1=Q.alpha[(n2+1)*3+1], al2=Q.alpha[(n2+1)*3+2];
      float An[16], Sp[16], Spi[16], Sf[16], T[16];
      #pragma unroll
      for(int k=0;k<16;k++){
        An[k]=al0*Q.Amat[k]+al1*Q.Amat[16+k]+al2*Q.Amat[32+k];
        Sp[k]=Q.Sigp[(n2+1)*16+k];
        Sf[k]=Q.Sigf[n2*16+k];
      }
      inv4_serial(Sp,Spi);
      #pragma unroll
      for(int r2=0;r2<4;r2++)
        #pragma unroll
        for(int c2=0;c2<4;c2++){
          float s2=0.f;
          #pragma unroll
          for(int k=0;k<4;k++) s2+=Sf[r2*4+k]*An[c2*4+k];
          T[r2*4+c2]=s2;
        }
      #pragma unroll
      for(int r2=0;r2<4;r2++)
        #pragma unroll
        for(int c2=0;c2<4;c2++){
          float s2=0.f;
          #pragma unroll
          for(int k=0;k<4;k++) s2+=T[r2*4+k]*Spi[k*4+c2];
          Q.Jb[n2*16+r2*4+c2]=s2;
        }
    }
    __syncthreads();
    // ---- RTS smoother scan (wave 0, wave-parallel) ----
    if (tid<64){
      const bool act=(r<4&&c<4);
      if (r<4&&c==0) out[OFF_MU+((size_t)127*32+b)*4+r]=Q.muf[127*4+r];
      if (act)       out[OFF_SG+((size_t)127*32+b)*16+r*4+c]=Q.Sigf[127*16+r*4+c];
      float ms0=Q.muf[508], ms1=Q.muf[509], ms2=Q.muf[510], ms3=Q.muf[511];
      float Ss=act?Q.Sigf[127*16+r*4+c]:0.f;
      for (int n2=126;n2>=0;n2--){
        float Jv =act?Q.Jb[n2*16+r*4+c]:0.f;
        float Sfv=act?Q.Sigf[n2*16+r*4+c]:0.f;
        float Spn=act?Q.Sigp[(n2+1)*16+r*4+c]:0.f;
        float Dv=Ss-Spn;
        float T2=0.f;
        #pragma unroll
        for(int k=0;k<4;k++) T2+=__shfl(Jv,(r<<3)|k,64)*__shfl(Dv,(k<<3)|c,64);
        float Sn=Sfv;
        #pragma unroll
        for(int k=0;k<4;k++) Sn+=__shfl(T2,(r<<3)|k,64)*__shfl(Jv,(c<<3)|k,64);
        float msc=(c==0)?ms0:((c==1)?ms1:((c==2)?ms2:ms3));
        float dmc=(c<4)?(msc-Q.muf[(n2+1)*4+(c&3)]):0.f;
        float p=Jv*dmc;
        p+=__shfl_xor(p,1,64); p+=__shfl_xor(p,2,64);
        float mun=Q.muf[n2*4+(r&3)]+p;
        if (r<4&&c==0) out[OFF_MU+((size_t)n2*32+b)*4+r]=mun;
        if (act)       out[OFF_SG+((size_t)n2*32+b)*16+r*4+c]=Sn;
        ms0=__shfl(mun,0,64); ms1=__shfl(mun,8,64); ms2=__shfl(mun,16,64); ms3=__shfl(mun,24,64);
        Ss=Sn;
      }
    }
    return;
  }

  // ================= decoder path (one image per block) =================
  DecSh& D = sh.d;
  const int n = blockIdx.x - 32;
  const int lane = tid & 63, wave = tid >> 6, g = lane >> 4, c15 = lane & 15;

  if (tid<8) D.aa[tid]=aglob[(size_t)n*8+tid];
  {
    uint4* dst=(uint4*)D.BT0;
    const uint4* src=(const uint4*)(ws16 + 2*RSZ);
    for (int i=tid;i<3552;i+=512) dst[i]=src[i];
  }
  if (tid<32){ D.d0T[9*AS+tid]=0; D.t0T[49*AS+tid]=0; D.t1T[225*AS+tid]=0; }
  __syncthreads();
  if (tid<288){
    float acc=bd[tid];
    #pragma unroll
    for(int j=0;j<8;j++) acc+=D.aa[j]*Wd[tid*8+j];
    D.d0T[(tid%9)*AS+(tid/9)]=f2bf(acc);
  }
  __syncthreads();
  // convT0 (MFMA)
  {
    const int mt=wave>>1, nt=wave&1;
    const int pa=mt*16+c15;
    const int oh=pa/7, ow=pa%7;
    const bool pv=(pa<49);
    f32x4 acc={0.f,0.f,0.f,0.f};
    #pragma unroll 1
    for (int kh=0;kh<3;kh++){
      int th=oh-kh;
      bool vh=pv && th>=0 && !(th&1) && th<=4;
      int ihb=(th>>1)*3;
      #pragma unroll
      for (int kw=0;kw<3;kw++){
        int tw=ow-kw;
        bool v=vh && tw>=0 && !(tw&1) && tw<=4;
        int pix=v?(ihb+(tw>>1)):9;
        bf16x8 af=*(const bf16x8*)&D.d0T[pix*AS+g*8];
        int tap=kh*3+kw;
        bf16x8 bb=*(const bf16x8*)&D.BT0[(nt*16+c15)*RS+tap*32+g*8];
        acc=MFMA16(af,bb,acc);
      }
    }
    float bz=bt0[nt*16+c15];
    #pragma unroll
    for (int r2=0;r2<4;r2++){
      int pc=mt*16+g*4+r2;
      if (pc<49) D.t0T[pc*AS+nt*16+c15]=f2bf(fmaxf(acc[r2]+bz,0.f));
    }
  }
  __syncthreads();
  // convT1 (MFMA)
  {
    float bA=bt1[c15], bB=bt1[c15+16];
    #pragma unroll 1
    for (int u2=0;u2<2;u2++){
      int unit=wave+u2*8;
      int cls=unit>>2, mt=unit&3;
      int ph=cls>>1, pw=cls&1;
      int ii=mt*2+(c15>>3), jj=c15&7;
      f32x4 acc0={0.f,0.f,0.f,0.f}, acc1={0.f,0.f,0.f,0.f};
      #pragma unroll 1
      for (int kh=ph;kh<3;kh+=2){
        int ih=ii-(kh>>1);
        #pragma unroll
        for (int kw=pw;kw<3;kw+=2){
          int iw=jj-(kw>>1);
          int pix=(ih>=0&&ih<7&&iw>=0&&iw<7)?(ih*7+iw):49;
          bf16x8 af=*(const bf16x8*)&D.t0T[pix*AS+g*8];
          int tap=kh*3+kw;
          bf16x8 b0=*(const bf16x8*)&D.BT1[c15*RS+tap*32+g*8];
          bf16x8 b1=*(const bf16x8*)&D.BT1[(c15+16)*RS+tap*32+g*8];
          acc0=MFMA16(af,b0,acc0);
          acc1=MFMA16(af,b1,acc1);
        }
      }
      #pragma unroll
      for (int r2=0;r2<4;r2++){
        int p16=g*4+r2;
        int iio=mt*2+(p16>>3), jjo=p16&7;
        int oh=2*iio+ph, ow=2*jjo+pw;
        if (oh<15 && ow<15){
          D.t1T[(oh*15+ow)*AS+c15]   =f2bf(fmaxf(acc0[r2]+bA,0.f));
          D.t1T[(oh*15+ow)*AS+c15+16]=f2bf(fmaxf(acc1[r2]+bB,0.f));
        }
      }
    }
  }
  __syncthreads();
  // convT2 (MFMA) fused head
  {
    float bt2a=bt2[c15], bt2b=bt2[c15+16], wga=Wg[c15], wgb=Wg[c15+16], bgv=bgp[0];
    #pragma unroll 1
    for (int u2=0;u2<2;u2++){
      int ii=wave+u2*8;
      #pragma unroll 1
      for (int cls=0;cls<4;cls++){
        int ph=cls>>1, pw=cls&1;
        f32x4 acc0={0.f,0.f,0.f,0.f}, acc1={0.f,0.f,0.f,0.f};
        #pragma unroll 1
        for (int kh=ph;kh<3;kh+=2){
          int ih=ii-(kh>>1);
          if (ih<0||ih>14) continue;
          #pragma unroll
          for (int kw=pw;kw<3;kw+=2){
            int iw=c15-(kw>>1);
            int pix=(iw>=0&&iw<15)?(ih*15+iw):225;
            bf16x8 af=*(const bf16x8*)&D.t1T[pix*AS+g*8];
            int tap=kh*3+kw;
            bf16x8 b0=*(const bf16x8*)&D.BT2[c15*RS+tap*32+g*8];
            bf16x8 b1=*(const bf16x8*)&D.BT2[(c15+16)*RS+tap*32+g*8];
            acc0=MFMA16(af,b0,acc0);
            acc1=MFMA16(af,b1,acc1);
          }
        }
        int oh=2*ii+ph;
        float s0=fmaxf(acc0[0]+bt2a,0.f)*wga+fmaxf(acc1[0]+bt2b,0.f)*wgb;
        float s1=fmaxf(acc0[1]+bt2a,0.f)*wga+fmaxf(acc1[1]+bt2b,0.f)*wgb;
        float s2=fmaxf(acc0[2]+bt2a,0.f)*wga+fmaxf(acc1[2]+bt2b,0.f)*wgb;
        float s3=fmaxf(acc0[3]+bt2a,0.f)*wga+fmaxf(acc1[3]+bt2b,0.f)*wgb;
        #pragma unroll
        for (int d=1;d<16;d<<=1){
          s0+=__shfl_xor(s0,d,64); s1+=__shfl_xor(s1,d,64);
          s2+=__shfl_xor(s2,d,64); s3+=__shfl_xor(s3,d,64);
        }
        if (c15==0){
          size_t ob=(size_t)n*1024+(size_t)oh*32+pw;
          out[ob+2*(g*4+0)]=sigm(s0+bgv);
          out[ob+2*(g*4+1)]=sigm(s1+bgv);
          out[ob+2*(g*4+2)]=sigm(s2+bgv);
          out[ob+2*(g*4+3)]=sigm(s3+bgv);
        }
      }
    }
  }
}

extern "C" void kernel_launch(void* const* d_in, const int* in_sizes, int n_in,
                              void* d_out, int out_size, void* d_ws, size_t ws_size,
                              hipStream_t stream)
{
  const float* x    =(const float*)d_in[0];
  const float* eps  =(const float*)d_in[1];
  const float* Wc0  =(const float*)d_in[2];
  const float* bc0  =(const float*)d_in[3];
  const float* Wc1  =(const float*)d_in[4];
  const float* bc1  =(const float*)d_in[5];
  const float* Wc2  =(const float*)d_in[6];
  const float* bc2  =(const float*)d_in[7];
  const float* Wm   =(const float*)d_in[8];
  const float* bm   =(const float*)d_in[9];
  const float* Wlv  =(const float*)d_in[10];
  const float* blv  =(const float*)d_in[11];
  const float* Wd   =(const float*)d_in[12];
  const float* bd   =(const float*)d_in[13];
  const float* Wt0  =(const float*)d_in[14];
  const float* bt0  =(const float*)d_in[15];
  const float* Wt1  =(const float*)d_in[16];
  const float* bt1  =(const float*)d_in[17];
  const float* Wt2  =(const float*)d_in[18];
  const float* bt2  =(const float*)d_in[19];
  const float* Wg   =(const float*)d_in[20];
  const float* bg   =(const float*)d_in[21];
  const float* A    =(const float*)d_in[22];
  const float* Bm   =(const float*)d_in[23];
  const float* Cm   =(const float*)d_in[24];
  const float* a0   =(const float*)d_in[25];
  const float* W_ih =(const float*)d_in[26];
  const float* W_hh =(const float*)d_in[27];
  const float* b_ih =(const float*)d_in[28];
  const float* b_hh =(const float*)d_in[29];
  const float* Wa   =(const float*)d_in[30];
  const float* ba   =(const float*)d_in[31];
  float* out=(float*)d_out;
  unsigned short* ws16=(unsigned short*)d_ws;

  k_prep<<<185,256,0,stream>>>(Wc1,Wc2,Wt0,Wt1,Wt2,ws16);
  k_enc<<<4096,256,0,stream>>>(x,eps,Wc0,bc0,bc1,bc2,Wm,bm,Wlv,blv,ws16,out);
  k_main<<<4128,512,0,stream>>>(Wd,bd,bt0,bt1,bt2,Wg,bg,A,Bm,Cm,a0,
                                W_ih,W_hh,b_ih,b_hh,Wa,ba,ws16,out);
}

// Round 16
// 312.545 us; speedup vs baseline: 1.3555x; 1.3555x over previous
//
#include <hip/hip_runtime.h>
#include <math.h>

#define DI __device__ __forceinline__

DI float sigm(float x){ return 1.0f/(1.0f+__expf(-x)); }
DI float tanhx(float x){ float ax=fabsf(x); float e=__expf(2.0f*ax); float t=1.0f-2.0f/(e+1.0f); return copysignf(t,x); }
DI unsigned short f2bf(float x){ unsigned u=__float_as_uint(x); return (unsigned short)((u+0x7fffu+((u>>16)&1u))>>16); }

typedef __attribute__((ext_vector_type(8))) short bf16x8;
typedef __attribute__((ext_vector_type(4))) float f32x4;
#define MFMA16(a,b,c) __builtin_amdgcn_mfma_f32_16x16x32_bf16(a,b,c,0,0,0)

static constexpr int RS  = 296;
static constexpr int RSZ = 9472;
static constexpr int AS  = 40;

static constexpr size_t OFF_A   = 4194304;
static constexpr size_t OFF_AM  = OFF_A   + 32768;
static constexpr size_t OFF_ALV = OFF_AM  + 32768;
static constexpr size_t OFF_MU  = OFF_ALV + 32768;
static constexpr size_t OFF_SG  = OFF_MU  + 16384;

// lane-parallel 4x4 inverse: valid at lanes (r<4,c<4); all 64 lanes execute.
DI float inv4_lane(float Mv, int r, int c){
  int a0=(c==0)?1:0, a1=(c<=1)?2:1, a2=(c<=2)?3:2;
  int b0=(r==0)?1:0, b1=(r<=1)?2:1, b2=(r<=2)?3:2;
  float m00=__shfl(Mv,(a0<<3)|b0,64), m01=__shfl(Mv,(a0<<3)|b1,64), m02=__shfl(Mv,(a0<<3)|b2,64);
  float m10=__shfl(Mv,(a1<<3)|b0,64), m11=__shfl(Mv,(a1<<3)|b1,64), m12=__shfl(Mv,(a1<<3)|b2,64);
  float m20=__shfl(Mv,(a2<<3)|b0,64), m21=__shfl(Mv,(a2<<3)|b1,64), m22=__shfl(Mv,(a2<<3)|b2,64);
  float det3 = m00*(m11*m22-m12*m21) - m01*(m10*m22-m12*m20) + m02*(m10*m21-m11*m20);
  float adj = (((r+c)&1)? -det3 : det3);
  float det=0.f;
  #pragma unroll
  for(int i=0;i<4;i++)
    det += __shfl(Mv,(i<<3),64)*__shfl(adj,i,64);
  return adj*(1.0f/det);
}

// serial 4x4 inverse (used only in parallel J precompute, one per thread)
DI void inv4_serial(const float* m, float* o){
  float i0 = m[5]*m[10]*m[15]-m[5]*m[11]*m[14]-m[9]*m[6]*m[15]+m[9]*m[7]*m[14]+m[13]*m[6]*m[11]-m[13]*m[7]*m[10];
  float i4 = -m[4]*m[10]*m[15]+m[4]*m[11]*m[14]+m[8]*m[6]*m[15]-m[8]*m[7]*m[14]-m[12]*m[6]*m[11]+m[12]*m[7]*m[10];
  float i8 = m[4]*m[9]*m[15]-m[4]*m[11]*m[13]-m[8]*m[5]*m[15]+m[8]*m[7]*m[13]+m[12]*m[5]*m[11]-m[12]*m[7]*m[9];
  float i12= -m[4]*m[9]*m[14]+m[4]*m[10]*m[13]+m[8]*m[5]*m[14]-m[8]*m[6]*m[13]-m[12]*m[5]*m[10]+m[12]*m[6]*m[9];
  float i1 = -m[1]*m[10]*m[15]+m[1]*m[11]*m[14]+m[9]*m[2]*m[15]-m[9]*m[3]*m[14]-m[13]*m[2]*m[11]+m[13]*m[3]*m[10];
  float i5 = m[0]*m[10]*m[15]-m[0]*m[11]*m[14]-m[8]*m[2]*m[15]+m[8]*m[3]*m[14]+m[12]*m[2]*m[11]-m[12]*m[3]*m[10];
  float i9 = -m[0]*m[9]*m[15]+m[0]*m[11]*m[13]+m[8]*m[1]*m[15]-m[8]*m[3]*m[13]-m[12]*m[1]*m[11]+m[12]*m[3]*m[9];
  float i13= m[0]*m[9]*m[14]-m[0]*m[10]*m[13]-m[8]*m[1]*m[14]+m[8]*m[2]*m[13]+m[12]*m[1]*m[10]-m[12]*m[2]*m[9];
  float i2 = m[1]*m[6]*m[15]-m[1]*m[7]*m[14]-m[5]*m[2]*m[15]+m[5]*m[3]*m[14]+m[13]*m[2]*m[7]-m[13]*m[3]*m[6];
  float i6 = -m[0]*m[6]*m[15]+m[0]*m[7]*m[14]+m[4]*m[2]*m[15]-m[4]*m[3]*m[14]-m[12]*m[2]*m[7]+m[12]*m[3]*m[6];
  float i10= m[0]*m[5]*m[15]-m[0]*m[7]*m[13]-m[4]*m[1]*m[15]+m[4]*m[3]*m[13]+m[12]*m[1]*m[7]-m[12]*m[3]*m[5];
  float i14= -m[0]*m[5]*m[14]+m[0]*m[6]*m[13]+m[4]*m[1]*m[14]-m[4]*m[2]*m[13]-m[12]*m[1]*m[6]+m[12]*m[2]*m[5];
  float i3 = -m[1]*m[6]*m[11]+m[1]*m[7]*m[10]+m[5]*m[2]*m[11]-m[5]*m[3]*m[10]-m[9]*m[2]*m[7]+m[9]*m[3]*m[6];
  float i7 = m[0]*m[6]*m[11]-m[0]*m[7]*m[10]-m[4]*m[2]*m[11]+m[4]*m[3]*m[10]+m[8]*m[2]*m[7]-m[8]*m[3]*m[6];
  float i11= -m[0]*m[5]*m[11]+m[0]*m[7]*m[9]+m[4]*m[1]*m[11]-m[4]*m[3]*m[9]-m[8]*m[1]*m[7]+m[8]*m[3]*m[5];
  float i15= m[0]*m[5]*m[10]-m[0]*m[6]*m[9]-m[4]*m[1]*m[10]+m[4]*m[2]*m[9]+m[8]*m[1]*m[6]-m[8]*m[2]*m[5];
  float rd=1.0f/(m[0]*i0+m[1]*i4+m[2]*i8+m[3]*i12);
  o[0]=i0*rd; o[1]=i1*rd; o[2]=i2*rd; o[3]=i3*rd;
  o[4]=i4*rd; o[5]=i5*rd; o[6]=i6*rd; o[7]=i7*rd;
  o[8]=i8*rd; o[9]=i9*rd; o[10]=i10*rd; o[11]=i11*rd;
  o[12]=i12*rd; o[13]=i13*rd; o[14]=i14*rd; o[15]=i15*rd;
}

// ===================== k_prep =====================
__global__ __launch_bounds__(256) void k_prep(
    const float* __restrict__ Wc1, const float* __restrict__ Wc2,
    const float* __restrict__ Wt0, const float* __restrict__ Wt1, const float* __restrict__ Wt2,
    unsigned short* __restrict__ ws16)
{
  int idx = blockIdx.x*256 + threadIdx.x;
  int mat = idx/RSZ, rem = idx%RSZ;
  int co = rem/RS, t = rem%RS;
  float v = 0.f;
  if (t < 288){
    int tap = t>>5, ci = t&31;
    if      (mat==0) v = Wc1[co*288+ci*9+tap];
    else if (mat==1) v = Wc2[co*288+ci*9+tap];
    else if (mat==2) v = Wt0[ci*288+co*9+tap];
    else if (mat==3) v = Wt1[ci*288+co*9+tap];
    else             v = Wt2[ci*288+co*9+tap];
  }
  ws16[idx] = f2bf(v);
}

// ===================== Encoder =====================
struct EncSh {
  alignas(16) float img[1024];
  alignas(16) unsigned short h0T[9040];
  alignas(16) unsigned short h1T[2000];
  alignas(16) unsigned short BT1e[9472];
  alignas(16) unsigned short BT2e[9472];
  alignas(16) float feat[288];
};

__global__ __launch_bounds__(256) void k_enc(
    const float* __restrict__ x, const float* __restrict__ eps,
    const float* __restrict__ Wc0, const float* __restrict__ bc0,
    const float* __restrict__ bc1, const float* __restrict__ bc2,
    const float* __restrict__ Wm, const float* __restrict__ bm,
    const float* __restrict__ Wlv, const float* __restrict__ blv,
    const unsigned short* __restrict__ ws16,
    float* __restrict__ out)
{
  __shared__ EncSh E;
  const int n = blockIdx.x, tid = threadIdx.x;
  const int lane = tid & 63, wave = tid >> 6, g = lane >> 4, c15 = lane & 15;

  for (int i=tid;i<1024;i+=256) E.img[i]=x[(size_t)n*1024+i];
  {
    uint4* dst=(uint4*)E.BT1e;
    const uint4* src=(const uint4*)ws16;
    for (int i=tid;i<2368;i+=256) dst[i]=src[i];
  }
  if (tid<32){ E.h0T[225*AS+tid]=0; E.h1T[49*AS+tid]=0; }
  __syncthreads();

  for (int i=tid;i<7200;i+=256){
    int co=i&31, p=i>>5, oy=p/15, ox=p%15;
    float acc=bc0[co];
    const float* wp=Wc0+co*9;
    int base=2*oy*32+2*ox;
    #pragma unroll
    for(int ky=0;ky<3;ky++)
      #pragma unroll
      for(int kx=0;kx<3;kx++)
        acc += E.img[base+ky*32+kx]*wp[ky*3+kx];
    E.h0T[p*AS+co]=f2bf(fmaxf(acc,0.0f));
  }
  __syncthreads();

  {
    const int mt=wave;
    const int oy=mt*2+(c15>>3), ox=c15&7;
    f32x4 acc0={0.f,0.f,0.f,0.f}, acc1={0.f,0.f,0.f,0.f};
    #pragma unroll 1
    for (int ky=0;ky<3;ky++){
      #pragma unroll
      for (int kx=0;kx<3;kx++){
        int iy=2*oy+ky, ix=2*ox+kx;
        int pix=(iy<15&&ix<15)?(iy*15+ix):225;
        bf16x8 af=*(const bf16x8*)&E.h0T[pix*AS+g*8];
        int tap=ky*3+kx;
        bf16x8 b0=*(const bf16x8*)&E.BT1e[c15*RS+tap*32+g*8];
        bf16x8 b1=*(const bf16x8*)&E.BT1e[(c15+16)*RS+tap*32+g*8];
        acc0=MFMA16(af,b0,acc0);
        acc1=MFMA16(af,b1,acc1);
      }
    }
    float bA=bc1[c15], bB=bc1[c15+16];
    #pragma unroll
    for (int r=0;r<4;r++){
      int p16=g*4+r, oy2=mt*2+(p16>>3), ox2=p16&7;
      if (oy2<7 && ox2<7){
        E.h1T[(oy2*7+ox2)*AS+c15]   =f2bf(fmaxf(acc0[r]+bA,0.f));
        E.h1T[(oy2*7+ox2)*AS+c15+16]=f2bf(fmaxf(acc1[r]+bB,0.f));
      }
    }
  }
  __syncthreads();

  if (wave<2){
    const int nt=wave;
    const int valid=(c15<9);
    const int oy=c15/3, ox=c15-oy*3;
    f32x4 acc={0.f,0.f,0.f,0.f};
    #pragma unroll 1
    for (int ky=0;ky<3;ky++){
      #pragma unroll
      for (int kx=0;kx<3;kx++){
        int pix=valid?((2*oy+ky)*7+(2*ox+kx)):49;
        bf16x8 af=*(const bf16x8*)&E.h1T[pix*AS+g*8];
        int tap=ky*3+kx;
        bf16x8 bfr=*(const bf16x8*)&E.BT2e[(nt*16+c15)*RS+tap*32+g*8];
        acc=MFMA16(af,bfr,acc);
      }
    }
    float bb=bc2[nt*16+c15];
    #pragma unroll
    for (int r=0;r<4;r++){
      int p16=g*4+r;
      if (p16<9) E.feat[(nt*16+c15)*9+p16]=fmaxf(acc[r]+bb,0.f);
    }
  }
  __syncthreads();

  if (tid<64){
    const int j=tid>>3, kk=tid&7;
    float s1=0.f,s2=0.f;
    const float* wm=Wm+j*288;
    const float* wl=Wlv+j*288;
    #pragma unroll 6
    for(int m=kk*36;m<kk*36+36;m++){ float f=E.feat[m]; s1+=f*wm[m]; s2+=f*wl[m]; }
    #pragma unroll
    for(int d=4;d>0;d>>=1){ s1+=__shfl_down(s1,d,64); s2+=__shfl_down(s2,d,64); }
    if(kk==0){
      size_t o=(size_t)n*8+j;
      float am=s1+bm[j];
      float lv=sigm(s2+blv[j]);
      float av=am+eps[o]*__expf(0.5f*lv);
      out[OFF_AM+o]=am;
      out[OFF_ALV+o]=lv;
      out[OFF_A+o]=av;
    }
  }
}

// ===================== k_main: 32 seq blocks + 4096 decoder blocks =====================
struct DecSh {
  alignas(16) float aa[8];
  alignas(16) unsigned short d0T[400];
  alignas(16) unsigned short t0T[2000];
  alignas(16) unsigned short t1T[9040];
  alignas(16) unsigned short BT0[9472];
  alignas(16) unsigned short BT1[9472];
  alignas(16) unsigned short BT2[9472];
};
struct SeqSh {
  alignas(16) float a_loc[1024];
  alignas(16) float a0[8];
  alignas(16) float h[56];
  float gates[200];
  float logit[4];
  float alpha[384];
  float muf[512];
  float Sigf[2048];
  float Sigp[2048];
  float Jb[2048];
  float Amat[48];
  float Bmat[96];
  float Cmat[96];
  float gram[96];
  float zk[1536];
  float Buk[1536];
  float mca[2048];   // [s][16]: Mc per step
  float zbu[1024];   // [s][8]: z[0..3], Bu[0..3]
};
union MainSh { DecSh d; SeqSh q; };

__global__ __launch_bounds__(512) void k_main(
    const float* __restrict__ Wd, const float* __restrict__ bd,
    const float* __restrict__ bt0, const float* __restrict__ bt1, const float* __restrict__ bt2,
    const float* __restrict__ Wg, const float* __restrict__ bgp,
    const float* __restrict__ Ag, const float* __restrict__ Bg, const float* __restrict__ Cg,
    const float* __restrict__ a_init,
    const float* __restrict__ W_ih, const float* __restrict__ W_hh,
    const float* __restrict__ b_ih, const float* __restrict__ b_hh,
    const float* __restrict__ Wa, const float* __restrict__ ba,
    const unsigned short* __restrict__ ws16,
    float* __restrict__ out)
{
  __shared__ MainSh sh;
  const int tid=threadIdx.x;
  const float* aglob = out + OFF_A;

  if (blockIdx.x < 32){
    // ================= sequential path (one batch per block; 5 waves) =================
    if (tid>=320) return;
    __builtin_amdgcn_s_setprio(1);
    SeqSh& Q = sh.q;
    const int b=blockIdx.x;
    for (int i=tid;i<1024;i+=320){ int s=i>>3, j=i&7; Q.a_loc[i]=aglob[((size_t)s*32+b)*8+j]; }
    if (tid<8)  Q.a0[tid]=a_init[tid];
    if (tid<56) Q.h[tid]=0.f;
    for (int i=tid;i<48;i+=320) Q.Amat[i]=Ag[i];
    for (int i=tid;i<96;i+=320){ Q.Bmat[i]=Bg[i]; Q.Cmat[i]=Cg[i]; }

    const int gr = tid-64;
    float wr[52], wi[8], bsum=0.f, creg=0.f;
    if (tid>=64 && tid<264){
      #pragma unroll
      for(int k=0;k<50;k++) wr[k]=W_hh[gr*50+k];
      wr[50]=0.f; wr[51]=0.f;
      #pragma unroll
      for(int j=0;j<8;j++) wi[j]=W_ih[gr*8+j];
      bsum=b_ih[gr]+b_hh[gr];
    }
    float wl[52]; float bl=0.f;
    if (tid>=264 && tid<267){
      #pragma unroll
      for(int k=0;k<50;k++) wl[k]=Wa[(tid-264)*50+k];
      wl[50]=0.f; wl[51]=0.f;
      bl=ba[tid-264];
    }
    // KF wave-0 constants/state
    const int r=tid>>3, c=tid&7;
    bool aid=false;
    if (tid<64){
      int ok=1;
      if (r<4&&c<4){
        float d=(r==c)?1.f:0.f;
        ok=(Ag[r*4+c]==d)&&(Ag[16+r*4+c]==d)&&(Ag[32+r*4+c]==d);
      }
      aid=(bool)__all(ok);
    }
    __syncthreads();
    // gram + zk/Buk tables
    if (tid<96){
      int which=tid>>4, e=tid&15, i2=e>>2, j2=e&3;
      float s2=0.f;
      if (which<3){
        const float* C=&Q.Cmat[which*32];
        #pragma unroll
        for(int m=0;m<8;m++) s2+=C[m*4+i2]*C[m*4+j2];
      } else {
        int k2=(which==5)?1:0, l2=(which==3)?1:2;
        const float* Ck=&Q.Cmat[k2*32];
        const float* Cl=&Q.Cmat[l2*32];
        #pragma unroll
        for(int m=0;m<8;m++) s2+=Ck[m*4+i2]*Cl[m*4+j2]+Cl[m*4+i2]*Ck[m*4+j2];
      }
      Q.gram[tid]=s2;
    }
    for (int idx=tid; idx<1536; idx+=320){
      int s=idx/12, r2=idx-s*12, k=r2>>2, i=r2&3;
      const float* Crow=&Q.Cmat[k*32];
      const float* Brow=&Q.Bmat[k*32+i*8];
      const float* av=&Q.a_loc[s*8];
      const float* uv=(s==0)?Q.a0:&Q.a_loc[(s-1)*8];
      float z2=0.f, bu=0.f;
      #pragma unroll
      for(int m=0;m<8;m++){ z2+=Crow[m*4+i]*av[m]; bu+=Brow[m]*uv[m]; }
      Q.zk[idx]=z2; Q.Buk[idx]=bu;
    }
    __syncthreads();

    // ---- LSTM loop over S=128 (waves 1-4; wave 0 idle) ----
    for (int s=0;s<128;s++){
      if (tid>=64 && tid<264){
        const float* ap=(s==0)?Q.a0:(Q.a_loc+(s-1)*8);
        float4 av0=*(const float4*)ap, av1=*(const float4*)(ap+4);
        float aA=bsum+av0.x*wi[0]+av0.y*wi[1]+av0.z*wi[2]+av0.w*wi[3]
                     +av1.x*wi[4]+av1.y*wi[5]+av1.z*wi[6]+av1.w*wi[7];
        float aB=0.f,aC=0.f,aD=0.f;
        #pragma unroll
        for(int q=0;q<13;q++){
          float4 hv=*(const float4*)&Q.h[4*q];
          aA+=hv.x*wr[4*q]; aB+=hv.y*wr[4*q+1]; aC+=hv.z*wr[4*q+2]; aD+=hv.w*wr[4*q+3];
        }
        Q.gates[gr]=(aA+aB)+(aC+aD);
      } else if (tid>=264 && tid<267){
        if (s>0){
          float aA=bl,aB=0.f,aC=0.f,aD=0.f;
          #pragma unroll
          for(int q=0;q<13;q++){
            float4 hv=*(const float4*)&Q.h[4*q];
            aA+=hv.x*wl[4*q]; aB+=hv.y*wl[4*q+1]; aC+=hv.z*wl[4*q+2]; aD+=hv.w*wl[4*q+3];
          }
          Q.logit[tid-264]=(aA+aB)+(aC+aD);
        }
      }
      __syncthreads();
      if (tid>=64 && tid<114){
        int j=gr;
        float ig=sigm(Q.gates[j]);
        float fg=sigm(Q.gates[50+j]);
        float gg=tanhx(Q.gates[100+j]);
        float og=sigm(Q.gates[150+j]);
        creg=fg*creg+ig*gg;
        Q.h[j]=og*tanhx(creg);
      } else if (tid>=114 && tid<117 && s>0){
        int j=tid-114;
        float l0=Q.logit[0], l1=Q.logit[1], l2=Q.logit[2];
        float mx=fmaxf(l0,fmaxf(l1,l2));
        float e0=__expf(l0-mx), e1=__expf(l1-mx), e2=__expf(l2-mx);
        float lj=(j==0)?l0:((j==1)?l1:l2);
        Q.alpha[(s-1)*3+j]=__expf(lj-mx)/(e0+e1+e2);
      }
      __syncthreads();
    }
    // ---- tail: logit/alpha 127 ----
    if (tid>=264 && tid<267){
      float aA=bl,aB=0.f,aC=0.f,aD=0.f;
      #pragma unroll
      for(int q=0;q<13;q++){
        float4 hv=*(const float4*)&Q.h[4*q];
        aA+=hv.x*wl[4*q]; aB+=hv.y*wl[4*q+1]; aC+=hv.z*wl[4*q+2]; aD+=hv.w*wl[4*q+3];
      }
      Q.logit[tid-264]=(aA+aB)+(aC+aD);
    }
    __syncthreads();
    if (tid<3){
      int j=tid;
      float l0=Q.logit[0], l1=Q.logit[1], l2=Q.logit[2];
      float mx=fmaxf(l0,fmaxf(l1,l2));
      float e0=__expf(l0-mx), e1=__expf(l1-mx), e2=__expf(l2-mx);
      float lj=(j==0)?l0:((j==1)?l1:l2);
      Q.alpha[127*3+j]=__expf(lj-mx)/(e0+e1+e2);
    }
    __syncthreads();
    // ---- all-step KF input tables: Mc[s][16], z/Bu[s][8] (parallel) ----
    for (int idx=tid; idx<2048; idx+=320){
      int s=idx>>4, e=idx&15;
      float al0=Q.alpha[s*3+0], al1=Q.alpha[s*3+1], al2=Q.alpha[s*3+2];
      Q.mca[idx]= al0*al0*Q.gram[e]    + al1*al1*Q.gram[16+e] + al2*al2*Q.gram[32+e]
                + al0*al1*Q.gram[48+e] + al0*al2*Q.gram[64+e] + al1*al2*Q.gram[80+e];
    }
    for (int idx=tid; idx<1024; idx+=320){
      int s=idx>>3, t=idx&7;
      float al0=Q.alpha[s*3+0], al1=Q.alpha[s*3+1], al2=Q.alpha[s*3+2];
      if (t<4) Q.zbu[idx]=al0*Q.zk[s*12+t]+al1*Q.zk[s*12+4+t]+al2*Q.zk[s*12+8+t];
      else {
        int i=t-4;
        Q.zbu[idx]=al0*Q.Buk[s*12+i]+al1*Q.Buk[s*12+4+i]+al2*Q.Buk[s*12+8+i];
      }
    }
    __syncthreads();
    // ---- KF loop (wave 0 only, BARRIER-FREE) ----
    if (tid<64){
      const bool act=(r<4&&c<4);
      const int cc=c&3, rr4=r&3;
      float mu0=0.f,mu1=0.f,mu2=0.f,mu3=0.f, Sg=0.f;
      for (int s3=0;s3<128;s3++){
        const float* mrow=&Q.mca[s3*16+cc*4];
        float mr0=mrow[0], mr1=mrow[1], mr2=mrow[2], mr3=mrow[3];
        float mc0=Q.mca[s3*16+cc], mc1=Q.mca[s3*16+4+cc], mc2=Q.mca[s3*16+8+cc], mc3=Q.mca[s3*16+12+cc];
        float zc=Q.zbu[s3*8+cc];
        float bu0=Q.zbu[s3*8+4], bu1=Q.zbu[s3*8+5], bu2=Q.zbu[s3*8+6], bu3=Q.zbu[s3*8+7];
        float mp0,mp1,mp2,mp3, Sp;
        if (aid){
          mp0=mu0+bu0; mp1=mu1+bu1; mp2=mu2+bu2; mp3=mu3+bu3;
          Sp=Sg+((r==c)?0.08f:0.f);
        } else {
          float al0=Q.alpha[s3*3+0], al1=Q.alpha[s3*3+1], al2=Q.alpha[s3*3+2];
          int e2=(rr4<<2)|cc;
          float At=al0*Q.Amat[e2]+al1*Q.Amat[16+e2]+al2*Q.Amat[32+e2];
          float mcc=(c==0)?mu0:((c==1)?mu1:((c==2)?mu2:((c==3)?mu3:0.f)));
          float qv=(c<4)?At*mcc:0.f;
          qv+=__shfl_xor(qv,1,64); qv+=__shfl_xor(qv,2,64);
          float bur=(rr4==0)?bu0:((rr4==1)?bu1:((rr4==2)?bu2:bu3));
          float rowv=qv+bur;
          mp0=__shfl(rowv,0,64); mp1=__shfl(rowv,8,64); mp2=__shfl(rowv,16,64); mp3=__shfl(rowv,24,64);
          float T=0.f;
          #pragma unroll
          for(int k=0;k<4;k++) T+=__shfl(At,(r<<3)|k,64)*__shfl(Sg,(k<<3)|c,64);
          float sp=0.f;
          #pragma unroll
          for(int k=0;k<4;k++) sp+=__shfl(T,(r<<3)|k,64)*__shfl(At,(c<<3)|k,64);
          Sp=sp+((r==c)?0.08f:0.f);
        }
        if (s3==0){ mp0=0.f;mp1=0.f;mp2=0.f;mp3=0.f; Sp=(r==c)?20.f:0.f; }
        if (act) Q.Sigp[s3*16+rr4*4+cc]=Sp;
        float wc=zc-(mr0*mp0+mr1*mp1+mr2*mp2+mr3*mp3);
        float gv=(r==c)?1.f:0.f;
        gv+=__shfl(Sp,(r<<3)|0,64)*mc0*(1.0f/0.03f);
        gv+=__shfl(Sp,(r<<3)|1,64)*mc1*(1.0f/0.03f);
        gv+=__shfl(Sp,(r<<3)|2,64)*mc2*(1.0f/0.03f);
        gv+=__shfl(Sp,(r<<3)|3,64)*mc3*(1.0f/0.03f);
        float Gi=inv4_lane(gv,r,c);
        float Sf=0.f;
        #pragma unroll
        for(int k=0;k<4;k++) Sf+=__shfl(Gi,(r<<3)|k,64)*__shfl(Sp,(k<<3)|c,64);
        if (act) Q.Sigf[s3*16+rr4*4+cc]=Sf;
        float p=(c<4)?Sf*wc:0.f;
        p+=__shfl_xor(p,1,64); p+=__shfl_xor(p,2,64);
        float mpr=(r==0)?mp0:((r==1)?mp1:((r==2)?mp2:mp3));
        float mufr=mpr+p*(1.0f/0.03f);
        if (r<4&&c==0) Q.muf[s3*4+r]=mufr;
        mu0=__shfl(mufr,0,64); mu1=__shfl(mufr,8,64); mu2=__shfl(mufr,16,64); mu3=__shfl(mufr,24,64);
        Sg=Sf;
      }
    }
    __syncthreads();
    // ---- RTS: J_n precompute (parallel over n) ----
    if (tid<127){
      const int n2=tid;
      float al0=Q.alpha[(n2+1)*3+0], al1=Q.alpha[(n2+1)*3+1], al2=Q.alpha[(n2+1)*3+2];
      float An[16], Sp[16], Spi[16], Sf[16], T[16];
      #pragma unroll
      for(int k=0;k<16;k++){
        An[k]=al0*Q.Amat[k]+al1*Q.Amat[16+k]+al2*Q.Amat[32+k];
        Sp[k]=Q.Sigp[(n2+1)*16+k];
        Sf[k]=Q.Sigf[n2*16+k];
      }
      inv4_serial(Sp,Spi);
      #pragma unroll
      for(int r2=0;r2<4;r2++)
        #pragma unroll
        for(int c2=0;c2<4;c2++){
          float s2=0.f;
          #pragma unroll
          for(int k=0;k<4;k++) s2+=Sf[r2*4+k]*An[c2*4+k];
          T[r2*4+c2]=s2;
        }
      #pragma unroll
      for(int r2=0;r2<4;r2++)
        #pragma unroll
        for(int c2=0;c2<4;c2++){
          float s2=0.f;
          #pragma unroll
          for(int k=0;k<4;k++) s2+=T[r2*4+k]*Spi[k*4+c2];
          Q.Jb[n2*16+r2*4+c2]=s2;
        }
    }
    __syncthreads();
    // ---- RTS smoother scan (wave 0, wave-parallel) ----
    if (tid<64){
      const bool act=(r<4&&c<4);
      if (r<4&&c==0) out[OFF_MU+((size_t)127*32+b)*4+r]=Q.muf[127*4+r];
      if (act)       out[OFF_SG+((size_t)127*32+b)*16+r*4+c]=Q.Sigf[127*16+r*4+c];
      float ms0=Q.muf[508], ms1=Q.muf[509], ms2=Q.muf[510], ms3=Q.muf[511];
      float Ss=act?Q.Sigf[127*16+r*4+c]:0.f;
      for (int n2=126;n2>=0;n2--){
        float Jv =act?Q.Jb[n2*16+r*4+c]:0.f;
        float Sfv=act?Q.Sigf[n2*16+r*4+c]:0.f;
        float Spn=act?Q.Sigp[(n2+1)*16+r*4+c]:0.f;
        float Dv=Ss-Spn;
        float T2=0.f;
        #pragma unroll
        for(int k=0;k<4;k++) T2+=__shfl(Jv,(r<<3)|k,64)*__shfl(Dv,(k<<3)|c,64);
        float Sn=Sfv;
        #pragma unroll
        for(int k=0;k<4;k++) Sn+=__shfl(T2,(r<<3)|k,64)*__shfl(Jv,(c<<3)|k,64);
        float msc=(c==0)?ms0:((c==1)?ms1:((c==2)?ms2:ms3));
        float dmc=(c<4)?(msc-Q.muf[(n2+1)*4+(c&3)]):0.f;
        float p=Jv*dmc;
        p+=__shfl_xor(p,1,64); p+=__shfl_xor(p,2,64);
        float mun=Q.muf[n2*4+(r&3)]+p;
        if (r<4&&c==0) out[OFF_MU+((size_t)n2*32+b)*4+r]=mun;
        if (act)       out[OFF_SG+((size_t)n2*32+b)*16+r*4+c]=Sn;
        ms0=__shfl(mun,0,64); ms1=__shfl(mun,8,64); ms2=__shfl(mun,16,64); ms3=__shfl(mun,24,64);
        Ss=Sn;
      }
    }
    return;
  }

  // ================= decoder path (one image per block) =================
  DecSh& D = sh.d;
  const int n = blockIdx.x - 32;
  const int lane = tid & 63, wave = tid >> 6, g = lane >> 4, c15 = lane & 15;

  if (tid<8) D.aa[tid]=aglob[(size_t)n*8+tid];
  {
    uint4* dst=(uint4*)D.BT0;
    const uint4* src=(const uint4*)(ws16 + 2*RSZ);
    for (int i=tid;i<3552;i+=512) dst[i]=src[i];
  }
  if (tid<32){ D.d0T[9*AS+tid]=0; D.t0T[49*AS+tid]=0; D.t1T[225*AS+tid]=0; }
  __syncthreads();
  if (tid<288){
    float acc=bd[tid];
    #pragma unroll
    for(int j=0;j<8;j++) acc+=D.aa[j]*Wd[tid*8+j];
    D.d0T[(tid%9)*AS+(tid/9)]=f2bf(acc);
  }
  __syncthreads();
  // convT0 (MFMA)
  {
    const int mt=wave>>1, nt=wave&1;
    const int pa=mt*16+c15;
    const int oh=pa/7, ow=pa%7;
    const bool pv=(pa<49);
    f32x4 acc={0.f,0.f,0.f,0.f};
    #pragma unroll 1
    for (int kh=0;kh<3;kh++){
      int th=oh-kh;
      bool vh=pv && th>=0 && !(th&1) && th<=4;
      int ihb=(th>>1)*3;
      #pragma unroll
      for (int kw=0;kw<3;kw++){
        int tw=ow-kw;
        bool v=vh && tw>=0 && !(tw&1) && tw<=4;
        int pix=v?(ihb+(tw>>1)):9;
        bf16x8 af=*(const bf16x8*)&D.d0T[pix*AS+g*8];
        int tap=kh*3+kw;
        bf16x8 bb=*(const bf16x8*)&D.BT0[(nt*16+c15)*RS+tap*32+g*8];
        acc=MFMA16(af,bb,acc);
      }
    }
    float bz=bt0[nt*16+c15];
    #pragma unroll
    for (int r2=0;r2<4;r2++){
      int pc=mt*16+g*4+r2;
      if (pc<49) D.t0T[pc*AS+nt*16+c15]=f2bf(fmaxf(acc[r2]+bz,0.f));
    }
  }
  __syncthreads();
  // convT1 (MFMA)
  {
    float bA=bt1[c15], bB=bt1[c15+16];
    #pragma unroll 1
    for (int u2=0;u2<2;u2++){
      int unit=wave+u2*8;
      int cls=unit>>2, mt=unit&3;
      int ph=cls>>1, pw=cls&1;
      int ii=mt*2+(c15>>3), jj=c15&7;
      f32x4 acc0={0.f,0.f,0.f,0.f}, acc1={0.f,0.f,0.f,0.f};
      #pragma unroll 1
      for (int kh=ph;kh<3;kh+=2){
        int ih=ii-(kh>>1);
        #pragma unroll
        for (int kw=pw;kw<3;kw+=2){
          int iw=jj-(kw>>1);
          int pix=(ih>=0&&ih<7&&iw>=0&&iw<7)?(ih*7+iw):49;
          bf16x8 af=*(const bf16x8*)&D.t0T[pix*AS+g*8];
          int tap=kh*3+kw;
          bf16x8 b0=*(const bf16x8*)&D.BT1[c15*RS+tap*32+g*8];
          bf16x8 b1=*(const bf16x8*)&D.BT1[(c15+16)*RS+tap*32+g*8];
          acc0=MFMA16(af,b0,acc0);
          acc1=MFMA16(af,b1,acc1);
        }
      }
      #pragma unroll
      for (int r2=0;r2<4;r2++){
        int p16=g*4+r2;
        int iio=mt*2+(p16>>3), jjo=p16&7;
        int oh=2*iio+ph, ow=2*jjo+pw;
        if (oh<15 && ow<15){
          D.t1T[(oh*15+ow)*AS+c15]   =f2bf(fmaxf(acc0[r2]+bA,0.f));
          D.t1T[(oh*15+ow)*AS+c15+16]=f2bf(fmaxf(acc1[r2]+bB,0.f));
        }
      }
    }
  }
  __syncthreads();
  // convT2 (MFMA) fused head
  {
    float bt2a=bt2[c15], bt2b=bt2[c15+16], wga=Wg[c15], wgb=Wg[c15+16], bgv=bgp[0];
    #pragma unroll 1
    for (int u2=0;u2<2;u2++){
      int ii=wave+u2*8;
      #pragma unroll 1
      for (int cls=0;cls<4;cls++){
        int ph=cls>>1, pw=cls&1;
        f32x4 acc0={0.f,0.f,0.f,0.f}, acc1={0.f,0.f,0.f,0.f};
        #pragma unroll 1
        for (int kh=ph;kh<3;kh+=2){
          int ih=ii-(kh>>1);
          if (ih<0||ih>14) continue;
          #pragma unroll
          for (int kw=pw;kw<3;kw+=2){
            int iw=c15-(kw>>1);
            int pix=(iw>=0&&iw<15)?(ih*15+iw):225;
            bf16x8 af=*(const bf16x8*)&D.t1T[pix*AS+g*8];
            int tap=kh*3+kw;
            bf16x8 b0=*(const bf16x8*)&D.BT2[c15*RS+tap*32+g*8];
            bf16x8 b1=*(const bf16x8*)&D.BT2[(c15+16)*RS+tap*32+g*8];
            acc0=MFMA16(af,b0,acc0);
            acc1=MFMA16(af,b1,acc1);
          }
        }
        int oh=2*ii+ph;
        float s0=fmaxf(acc0[0]+bt2a,0.f)*wga+fmaxf(acc1[0]+bt2b,0.f)*wgb;
        float s1=fmaxf(acc0[1]+bt2a,0.f)*wga+fmaxf(acc1[1]+bt2b,0.f)*wgb;
        float s2=fmaxf(acc0[2]+bt2a,0.f)*wga+fmaxf(acc1[2]+bt2b,0.f)*wgb;
        float s3=fmaxf(acc0[3]+bt2a,0.f)*wga+fmaxf(acc1[3]+bt2b,0.f)*wgb;
        #pragma unroll
        for (int d=1;d<16;d<<=1){
          s0+=__shfl_xor(s0,d,64); s1+=__shfl_xor(s1,d,64);
          s2+=__shfl_xor(s2,d,64); s3+=__shfl_xor(s3,d,64);
        }
        if (c15==0){
          size_t ob=(size_t)n*1024+(size_t)oh*32+pw;
          out[ob+2*(g*4+0)]=sigm(s0+bgv);
          out[ob+2*(g*4+1)]=sigm(s1+bgv);
          out[ob+2*(g*4+2)]=sigm(s2+bgv);
          out[ob+2*(g*4+3)]=sigm(s3+bgv);
        }
      }
    }
  }
}

extern "C" void kernel_launch(void* const* d_in, const int* in_sizes, int n_in,
                              void* d_out, int out_size, void* d_ws, size_t ws_size,
                              hipStream_t stream)
{
  const float* x    =(const float*)d_in[0];
  const float* eps  =(const float*)d_in[1];
  const float* Wc0  =(const float*)d_in[2];
  const float* bc0  =(const float*)d_in[3];
  const float* Wc1  =(const float*)d_in[4];
  const float* bc1  =(const float*)d_in[5];
  const float* Wc2  =(const float*)d_in[6];
  const float* bc2  =(const float*)d_in[7];
  const float* Wm   =(const float*)d_in[8];
  const float* bm   =(const float*)d_in[9];
  const float* Wlv  =(const float*)d_in[10];
  const float* blv  =(const float*)d_in[11];
  const float* Wd   =(const float*)d_in[12];
  const float* bd   =(const float*)d_in[13];
  const float* Wt0  =(const float*)d_in[14];
  const float* bt0  =(const float*)d_in[15];
  const float* Wt1  =(const float*)d_in[16];
  const float* bt1  =(const float*)d_in[17];
  const float* Wt2  =(const float*)d_in[18];
  const float* bt2  =(const float*)d_in[19];
  const float* Wg   =(const float*)d_in[20];
  const float* bg   =(const float*)d_in[21];
  const float* A    =(const float*)d_in[22];
  const float* Bm   =(const float*)d_in[23];
  const float* Cm   =(const float*)d_in[24];
  const float* a0   =(const float*)d_in[25];
  const float* W_ih =(const float*)d_in[26];
  const float* W_hh =(const float*)d_in[27];
  const float* b_ih =(const float*)d_in[28];
  const float* b_hh =(const float*)d_in[29];
  const float* Wa   =(const float*)d_in[30];
  const float* ba   =(const float*)d_in[31];
  float* out=(float*)d_out;
  unsigned short* ws16=(unsigned short*)d_ws;

  k_prep<<<185,256,0,stream>>>(Wc1,Wc2,Wt0,Wt1,Wt2,ws16);
  k_enc<<<4096,256,0,stream>>>(x,eps,Wc0,bc0,bc1,bc2,Wm,bm,Wlv,blv,ws16,out);
  k_main<<<4128,512,0,stream>>>(Wd,bd,bt0,bt1,bt2,Wg,bg,A,Bm,Cm,a0,
                                W_ih,W_hh,b_ih,b_hh,Wa,ba,ws16,out);
}